// Round 4
// baseline (557.387 us; speedup 1.0000x reference)
//
#include <hip/hip_runtime.h>

#define T_TOK 4096
#define H_DIM 1024
#define I_DIM 4096
#define NE 8

typedef _Float16 f16;
typedef _Float16 f16x8 __attribute__((ext_vector_type(8)));
typedef _Float16 f16x4 __attribute__((ext_vector_type(4)));
typedef float f32x4 __attribute__((ext_vector_type(4)));

#define GLOBAL_AS __attribute__((address_space(1)))
#define LDS_AS __attribute__((address_space(3)))

__device__ __forceinline__ void gload_lds16(const void* g, void* l) {
  __builtin_amdgcn_global_load_lds((GLOBAL_AS const unsigned int*)g,
                                   (LDS_AS unsigned int*)l, 16, 0, 0);
}

// counted waits — "memory" clobber pins LDS reads / staging issues to their phase
#define VM6() asm volatile("s_waitcnt vmcnt(6)" ::: "memory")
#define VM4() asm volatile("s_waitcnt vmcnt(4)" ::: "memory")
#define VM0() asm volatile("s_waitcnt vmcnt(0)" ::: "memory")
#define BAR() __builtin_amdgcn_s_barrier()

// ---------------------------------------------------------------- cast x -> fp16
__global__ void cast_x_kernel(const float* __restrict__ x, f16* __restrict__ xh) {
  int i = blockIdx.x * 256 + threadIdx.x;
  float4 v = reinterpret_cast<const float4*>(x)[i];
  f16x4 o = {(f16)v.x, (f16)v.y, (f16)v.z, (f16)v.w};
  reinterpret_cast<f16x4*>(xh)[i] = o;
}

// ---------------------------------------------------------------- transpose+cast (all 3 weights, 24 z-slices)
__global__ __launch_bounds__(256) void transpose_cast_kernel(
    const float* __restrict__ w1s, const float* __restrict__ w3s,
    const float* __restrict__ w2s, f16* __restrict__ w1t,
    f16* __restrict__ w3t, f16* __restrict__ w2t) {
  __shared__ float tile[64][65];
  const int z = blockIdx.z;
  const float* in;
  f16* out;
  int R, C, r0, c0;
  if (z < 16) {  // w1 (z<8) / w3 : [H][I] -> [I][H]
    int e = z & 7;
    in = (z < 8 ? w1s : w3s) + (size_t)e * H_DIM * I_DIM;
    out = (z < 8 ? w1t : w3t) + (size_t)e * H_DIM * I_DIM;
    R = H_DIM; C = I_DIM;
    c0 = blockIdx.x * 64; r0 = blockIdx.y * 64;
  } else {       // w2: [I][H] -> [H][I]
    int e = z - 16;
    in = w2s + (size_t)e * H_DIM * I_DIM;
    out = w2t + (size_t)e * H_DIM * I_DIM;
    R = I_DIM; C = H_DIM;
    r0 = blockIdx.x * 64; c0 = blockIdx.y * 64;
  }
  const int tr = threadIdx.x >> 4;
  const int tc = (threadIdx.x & 15) * 4;
#pragma unroll
  for (int i = 0; i < 4; ++i) {
    int r = tr + i * 16;
    float4 v = *reinterpret_cast<const float4*>(&in[(size_t)(r0 + r) * C + c0 + tc]);
    tile[r][tc] = v.x; tile[r][tc + 1] = v.y; tile[r][tc + 2] = v.z; tile[r][tc + 3] = v.w;
  }
  __syncthreads();
#pragma unroll
  for (int i = 0; i < 4; ++i) {
    int oc = tr + i * 16;
    f16x4 h;
#pragma unroll
    for (int j = 0; j < 4; ++j) h[j] = (f16)tile[tc + j][oc];
    *reinterpret_cast<f16x4*>(&out[(size_t)(c0 + oc) * R + r0 + tc]) = h;
  }
}

// ---------------------------------------------------------------- router (1 wave / token)
__global__ void router_kernel(const float* __restrict__ x, const float* __restrict__ gw,
                              int* __restrict__ counts, int* __restrict__ lists,
                              float* __restrict__ wgts) {
  const int t = blockIdx.x;
  const int l = threadIdx.x;
  const float* xr = x + (size_t)t * H_DIM;
  float acc[NE];
#pragma unroll
  for (int e = 0; e < NE; ++e) acc[e] = 0.f;
  for (int k = l; k < H_DIM; k += 64) {
    float xv = xr[k];
#pragma unroll
    for (int e = 0; e < NE; ++e) acc[e] += xv * gw[k * NE + e];
  }
#pragma unroll
  for (int e = 0; e < NE; ++e) {
    float v = acc[e];
#pragma unroll
    for (int off = 32; off > 0; off >>= 1) v += __shfl_xor(v, off);
    acc[e] = v;
  }
  if (l == 0) {
    int i1 = 0;
#pragma unroll
    for (int e = 1; e < NE; ++e)
      if (acc[e] > acc[i1]) i1 = e;
    int i2 = (i1 == 0) ? 1 : 0;
#pragma unroll
    for (int e = 0; e < NE; ++e)
      if (e != i1 && acc[e] > acc[i2]) i2 = e;
    float wA = 1.f / (1.f + __expf(acc[i2] - acc[i1]));
    float wB = 1.f - wA;
    int p1 = atomicAdd(&counts[i1], 1);
    lists[i1 * T_TOK + p1] = t;
    wgts[i1 * T_TOK + p1] = wA;
    int p2 = atomicAdd(&counts[i2], 1);
    lists[i2 * T_TOK + p2] = t;
    wgts[i2 * T_TOK + p2] = wB;
  }
}

// ---------------------------------------------------------------- padded prefix offsets
__global__ void prefix_kernel(const int* __restrict__ counts, int* __restrict__ bases) {
  if (threadIdx.x == 0) {
    int s = 0;
#pragma unroll
    for (int e = 0; e < NE; ++e) {
      bases[e] = s;
      s += (counts[e] + 127) & ~127;
    }
  }
}

// ---------------------------------------------------------------- GEMM A: inter = silu(x@w1)*(x@w3)
// 512 thr (8 waves 2Mx4N), tile 128rows x 128cols(dual), BK=64.
// 3-slot LDS ring, staged 2 K-tiles ahead, counted vmcnt(6) + raw barrier per tile.
__global__ __launch_bounds__(512, 1) void gemm_a_kernel(
    const f16* __restrict__ xh, const f16* __restrict__ w1t, const f16* __restrict__ w3t,
    const int* __restrict__ counts, const int* __restrict__ bases,
    const int* __restrict__ lists, f16* __restrict__ inter) {
  const int z = blockIdx.z;
  const int cnt = counts[z];
  const int r0 = blockIdx.y * 128;
  if (r0 >= cnt) return;
  const int base = bases[z];
  const int c0 = blockIdx.x * 128;
  const int tid = threadIdx.x;
  const int lane = tid & 63;
  const int wid = tid >> 6;           // 0..7
  const int wm = wid >> 2, wn = wid & 3;
  const int lrow = lane & 15, lk = lane >> 4;

  // ring slot = A[128][64] + B1[128][64] + B3[128][64] = 24576 f16 = 48 KiB; x3 = 144 KiB
  __shared__ __align__(16) f16 ring[3][24576];

  const int* lst = lists + z * T_TOK;
  const f16* w1 = w1t + (size_t)z * H_DIM * I_DIM;
  const f16* w3 = w3t + (size_t)z * H_DIM * I_DIM;

  // per-thread staging sources (inverse-swizzled source slot; LDS dest linear)
  const f16 *asrc[2], *b1src[2], *b3src[2];
#pragma unroll
  for (int i = 0; i < 2; ++i) {
    int sf = i * 512 + tid;
    int row = sf >> 3;
    int s = sf & 7;
    int cofs = (s ^ (row & 7)) * 8;
    int tok = lst[r0 + row];          // zeroed past cnt -> token 0 (safe pad)
    asrc[i] = xh + (size_t)tok * H_DIM + cofs;
    b1src[i] = w1 + (size_t)(c0 + row) * H_DIM + cofs;
    b3src[i] = w3 + (size_t)(c0 + row) * H_DIM + cofs;
  }

#define STAGE_A(SB, K0)                                              \
  do {                                                               \
    _Pragma("unroll") for (int i_ = 0; i_ < 2; ++i_) {               \
      int dofs = (i_ * 512 + (wid << 6)) * 8;                        \
      gload_lds16(asrc[i_] + (K0), (SB) + dofs);                     \
      gload_lds16(b1src[i_] + (K0), (SB) + 8192 + dofs);             \
      gload_lds16(b3src[i_] + (K0), (SB) + 16384 + dofs);            \
    }                                                                \
  } while (0)

  const f32x4 z4 = {0.f, 0.f, 0.f, 0.f};
  f32x4 acc1[4][2], acc3[4][2];
#pragma unroll
  for (int m = 0; m < 4; ++m)
#pragma unroll
    for (int n = 0; n < 2; ++n) { acc1[m][n] = z4; acc3[m][n] = z4; }

  f16 *s0 = ring[0], *s1 = ring[1], *s2 = ring[2];
  const int NT = H_DIM / 64;  // 16
  STAGE_A(s0, 0);
  STAGE_A(s1, 64);
  VM6();                      // own tile-0 loads done (6 of 12 outstanding remain)
  BAR();

  for (int t = 0; t < NT; ++t) {
    if (t + 2 < NT) STAGE_A(s2, (t + 2) * 64);
#pragma unroll
    for (int kk = 0; kk < 2; ++kk) {
      const int cs = kk * 4 + lk;
      f16x8 af[4], b1f[2], b3f[2];
#pragma unroll
      for (int m = 0; m < 4; ++m) {
        int row = wm * 64 + m * 16 + lrow;
        af[m] = *reinterpret_cast<const f16x8*>(&s0[row * 64 + ((cs ^ (row & 7)) * 8)]);
      }
#pragma unroll
      for (int n = 0; n < 2; ++n) {
        int row = wn * 32 + n * 16 + lrow;
        int off = row * 64 + ((cs ^ (row & 7)) * 8);
        b1f[n] = *reinterpret_cast<const f16x8*>(&s0[8192 + off]);
        b3f[n] = *reinterpret_cast<const f16x8*>(&s0[16384 + off]);
      }
#pragma unroll
      for (int m = 0; m < 4; ++m)
#pragma unroll
        for (int n = 0; n < 2; ++n) {
          acc1[m][n] = __builtin_amdgcn_mfma_f32_16x16x32_f16(af[m], b1f[n], acc1[m][n], 0, 0, 0);
          acc3[m][n] = __builtin_amdgcn_mfma_f32_16x16x32_f16(af[m], b3f[n], acc3[m][n], 0, 0, 0);
        }
    }
    if (t + 2 < NT) VM6(); else VM0();
    BAR();
    f16* tmp = s0; s0 = s1; s1 = s2; s2 = tmp;
  }
#undef STAGE_A

  // epilogue: SwiGLU, fp16 store (pad rows hold garbage; never combined)
#pragma unroll
  for (int m = 0; m < 4; ++m)
#pragma unroll
    for (int n = 0; n < 2; ++n)
#pragma unroll
      for (int r = 0; r < 4; ++r) {
        int grow = base + r0 + wm * 64 + m * 16 + lk * 4 + r;
        int gcol = c0 + wn * 32 + n * 16 + lrow;
        float sv1 = acc1[m][n][r];
        float sv3 = acc3[m][n][r];
        float sv = sv1 / (1.f + __expf(-sv1));
        inter[(size_t)grow * I_DIM + gcol] = (f16)(sv * sv3);
      }
}

// ---------------------------------------------------------------- GEMM B: out[tok] += wgt * inter@w2
// Same ring structure; tile 128x128, BK=64, NT=64, vmcnt(4).
__global__ __launch_bounds__(512, 1) void gemm_b_kernel(
    const f16* __restrict__ inter, const f16* __restrict__ w2t,
    const int* __restrict__ counts, const int* __restrict__ bases,
    const int* __restrict__ lists, const float* __restrict__ wgts,
    float* __restrict__ out) {
  const int z = blockIdx.z;
  const int cnt = counts[z];
  const int r0 = blockIdx.y * 128;
  if (r0 >= cnt) return;
  const int base = bases[z];
  const int c0 = blockIdx.x * 128;
  const int tid = threadIdx.x;
  const int lane = tid & 63;
  const int wid = tid >> 6;
  const int wm = wid >> 2, wn = wid & 3;
  const int lrow = lane & 15, lk = lane >> 4;

  // ring slot = A[128][64] + B[128][64] = 16384 f16 = 32 KiB; x3 = 96 KiB
  __shared__ __align__(16) f16 ring[3][16384];

  const int* lst = lists + z * T_TOK;
  const float* wgt = wgts + z * T_TOK;
  const f16* w2 = w2t + (size_t)z * I_DIM * H_DIM;

  const f16 *asrc[2], *bsrc[2];
#pragma unroll
  for (int i = 0; i < 2; ++i) {
    int sf = i * 512 + tid;
    int row = sf >> 3;
    int s = sf & 7;
    int cofs = (s ^ (row & 7)) * 8;
    asrc[i] = inter + (size_t)(base + r0 + row) * I_DIM + cofs;
    bsrc[i] = w2 + (size_t)(c0 + row) * I_DIM + cofs;
  }

#define STAGE_B(SB, K0)                                              \
  do {                                                               \
    _Pragma("unroll") for (int i_ = 0; i_ < 2; ++i_) {               \
      int dofs = (i_ * 512 + (wid << 6)) * 8;                        \
      gload_lds16(asrc[i_] + (K0), (SB) + dofs);                     \
      gload_lds16(bsrc[i_] + (K0), (SB) + 8192 + dofs);              \
    }                                                                \
  } while (0)

  const f32x4 z4 = {0.f, 0.f, 0.f, 0.f};
  f32x4 acc[4][2];
#pragma unroll
  for (int m = 0; m < 4; ++m)
#pragma unroll
    for (int n = 0; n < 2; ++n) acc[m][n] = z4;

  f16 *s0 = ring[0], *s1 = ring[1], *s2 = ring[2];
  const int NT = I_DIM / 64;  // 64
  STAGE_B(s0, 0);
  STAGE_B(s1, 64);
  VM4();
  BAR();

  for (int t = 0; t < NT; ++t) {
    if (t + 2 < NT) STAGE_B(s2, (t + 2) * 64);
#pragma unroll
    for (int kk = 0; kk < 2; ++kk) {
      const int cs = kk * 4 + lk;
      f16x8 af[4], bf[2];
#pragma unroll
      for (int m = 0; m < 4; ++m) {
        int row = wm * 64 + m * 16 + lrow;
        af[m] = *reinterpret_cast<const f16x8*>(&s0[row * 64 + ((cs ^ (row & 7)) * 8)]);
      }
#pragma unroll
      for (int n = 0; n < 2; ++n) {
        int row = wn * 32 + n * 16 + lrow;
        bf[n] = *reinterpret_cast<const f16x8*>(&s0[8192 + row * 64 + ((cs ^ (row & 7)) * 8)]);
      }
#pragma unroll
      for (int m = 0; m < 4; ++m)
#pragma unroll
        for (int n = 0; n < 2; ++n)
          acc[m][n] = __builtin_amdgcn_mfma_f32_16x16x32_f16(af[m], bf[n], acc[m][n], 0, 0, 0);
    }
    if (t + 2 < NT) VM4(); else VM0();
    BAR();
    f16* tmp = s0; s0 = s1; s1 = s2; s2 = tmp;
  }
#undef STAGE_B

  // epilogue: ATOMIC accumulate (same token in two experts' lists; blocks concurrent)
#pragma unroll
  for (int m = 0; m < 4; ++m)
#pragma unroll
    for (int r = 0; r < 4; ++r) {
      int ri = r0 + wm * 64 + m * 16 + lk * 4 + r;
      if (ri < cnt) {
        int tok = lst[ri];
        float wg = wgt[ri];
        float* orow = out + (size_t)tok * H_DIM + c0 + wn * 32 + lrow;
#pragma unroll
        for (int n = 0; n < 2; ++n) atomicAdd(&orow[n * 16], wg * acc[m][n][r]);
      }
    }
}

// ---------------------------------------------------------------- host
extern "C" void kernel_launch(void* const* d_in, const int* in_sizes, int n_in,
                              void* d_out, int out_size, void* d_ws, size_t ws_size,
                              hipStream_t stream) {
  const float* x = (const float*)d_in[0];
  const float* gw = (const float*)d_in[1];
  const float* w1s = (const float*)d_in[2];
  const float* w2s = (const float*)d_in[3];
  const float* w3s = (const float*)d_in[4];
  float* out = (float*)d_out;

  char* ws = (char*)d_ws;
  f16* xh = (f16*)ws;                                   // 8 MiB
  f16* inter = (f16*)(ws + ((size_t)8 << 20));          // 72 MiB
  f16* w1t = (f16*)(ws + ((size_t)80 << 20));           // 64 MiB
  f16* w3t = (f16*)(ws + ((size_t)144 << 20));          // 64 MiB
  f16* w2t = (f16*)(ws + ((size_t)208 << 20));          // 64 MiB
  char* meta = ws + ((size_t)272 << 20);
  int* counts = (int*)meta;
  int* bases = (int*)(meta + 512);
  int* lists = (int*)(meta + 1024);
  float* wgts = (float*)(meta + 1024 + (size_t)NE * T_TOK * 4);

  hipMemsetAsync(out, 0, (size_t)out_size * sizeof(float), stream);
  hipMemsetAsync(meta, 0, 1024 + (size_t)NE * T_TOK * 8, stream);

  cast_x_kernel<<<dim3((T_TOK * H_DIM) / (4 * 256)), dim3(256), 0, stream>>>(x, xh);
  router_kernel<<<dim3(T_TOK), dim3(64), 0, stream>>>(x, gw, counts, lists, wgts);
  prefix_kernel<<<dim3(1), dim3(64), 0, stream>>>(counts, bases);
  transpose_cast_kernel<<<dim3(64, 16, 24), dim3(256), 0, stream>>>(
      w1s, w3s, w2s, w1t, w3t, w2t);
  gemm_a_kernel<<<dim3(I_DIM / 128, T_TOK / 128, NE), dim3(512), 0, stream>>>(
      xh, w1t, w3t, counts, bases, lists, inter);
  gemm_b_kernel<<<dim3(H_DIM / 128, T_TOK / 128, NE), dim3(512), 0, stream>>>(
      inter, w2t, counts, bases, lists, wgts, out);
}